// Round 2
// baseline (3152.998 us; speedup 1.0000x reference)
//
#include <hip/hip_runtime.h>
#include <cmath>

#define S_CNT 50
#define T_CNT 2048
#define I_DIM 64
#define H_DIM 256
#define CH    32
#define NTHR  512

__device__ __forceinline__ float fast_tanh(float x) {
    float e = __expf(2.0f * x);
    return 1.0f - __fdividef(2.0f, e + 1.0f);
}

__device__ __forceinline__ float fma4(const float4 w, const float4 h, float a) {
    a = fmaf(w.x, h.x, a);
    a = fmaf(w.y, h.y, a);
    a = fmaf(w.z, h.z, a);
    a = fmaf(w.w, h.w, a);
    return a;
}

// U[s][t][j] = b_ih[s][j] + b_hh[s][j] + W_ih[s][j]·x[s][t]
__launch_bounds__(256, 4)
__global__ void precompute_u_kernel(const float* __restrict__ input_data,
                                    const float* __restrict__ W_ih,
                                    const float* __restrict__ b_ih,
                                    const float* __restrict__ b_hh,
                                    float* __restrict__ U)
{
    const int s  = blockIdx.x;
    const int tb = blockIdx.y;   // t-quarter
    const int j  = threadIdx.x;

    float4 w[16];
    const float4* wrow =
        reinterpret_cast<const float4*>(W_ih + ((size_t)s * H_DIM + j) * I_DIM);
#pragma unroll
    for (int k = 0; k < 16; ++k) w[k] = wrow[k];
    const float bsum = b_ih[s * H_DIM + j] + b_hh[s * H_DIM + j];

    __shared__ float xs[CH][I_DIM];
    const float* inb = input_data + (size_t)s * T_CNT * 65;
    float* Ub = U + (size_t)s * T_CNT * H_DIM;

    for (int c = 0; c < 16; ++c) {
        const int t0 = tb * 512 + c * CH;
        __syncthreads();
        for (int idx = j; idx < CH * I_DIM; idx += 256) {
            const int row = idx >> 6, col = idx & 63;
            xs[row][col] = inb[(size_t)(t0 + row) * 65 + 1 + col];
        }
        __syncthreads();
        for (int tt = 0; tt < CH; ++tt) {
            const float4* xv = reinterpret_cast<const float4*>(&xs[tt][0]);
            float a0 = bsum, a1 = 0.f, a2 = 0.f, a3 = 0.f;
#pragma unroll
            for (int k = 0; k < 16; k += 4) {
                a0 = fma4(w[k],     xv[k],     a0);
                a1 = fma4(w[k + 1], xv[k + 1], a1);
                a2 = fma4(w[k + 2], xv[k + 2], a2);
                a3 = fma4(w[k + 3], xv[k + 3], a3);
            }
            Ub[(size_t)(t0 + tt) * H_DIM + j] = (a0 + a1) + (a2 + a3);
        }
    }
}

// Layout: tid = j*2 + half. Thread computes W_hh[j][half*128 .. +128)·h.
// 1-stage pair reduce; sigma-reduce pipelined one step behind; thread0
// finalize two steps behind.
template <bool USE_U>
__launch_bounds__(NTHR, 2)
__global__ void rnn_main_kernel(const float* __restrict__ input_data,
                                const float* __restrict__ hidden,
                                const float* __restrict__ fe,
                                const float* __restrict__ W_ih,
                                const float* __restrict__ W_hh,
                                const float* __restrict__ b_ih,
                                const float* __restrict__ b_hh,
                                const float* __restrict__ W_lin,
                                const float* __restrict__ b_lin,
                                const float* __restrict__ U,
                                float* __restrict__ out)
{
    const int s    = blockIdx.x;
    const int tid  = threadIdx.x;
    const int j    = tid >> 1;
    const int half = tid & 1;
    const int lane = tid & 63;
    const int wv   = tid >> 6;

    __shared__ float hbuf[2][H_DIM];
    __shared__ float ubuf[CH][H_DIM];   // USE_U path
    __shared__ float xbuf[CH][I_DIM];   // fallback path
    __shared__ float zbuf[2][CH];
    __shared__ float febuf[2][CH];
    __shared__ float wsum[2][8];
    __shared__ float wlin_lds[H_DIM];
    __shared__ float bias_lds[H_DIM];

    for (int k = tid; k < H_DIM; k += NTHR) {
        hbuf[1][k]  = hidden[s * H_DIM + k];
        wlin_lds[k] = W_lin[s * H_DIM + k];
        if (!USE_U) bias_lds[k] = b_ih[s * H_DIM + k] + b_hh[s * H_DIM + k];
    }

    // W_hh half-row into registers: 32 float4 = 128 VGPR
    float4 whh[32];
    {
        const float4* wrow =
            reinterpret_cast<const float4*>(W_hh + ((size_t)s * H_DIM + j) * H_DIM) +
            half * 32;
#pragma unroll
        for (int q = 0; q < 32; ++q) whh[q] = wrow[q];
    }
    float4 wih[8];
    if (!USE_U) {
        const float4* wxrow =
            reinterpret_cast<const float4*>(W_ih + ((size_t)s * H_DIM + j) * I_DIM) +
            half * 8;
#pragma unroll
        for (int q = 0; q < 8; ++q) wih[q] = wxrow[q];
    }

    const float blin = b_lin[s];
    float ll = 0.f, sv_prev = 0.f;
    float* sig_out       = out + 1 + (size_t)s * T_CNT;
    const float* in_base = input_data + (size_t)s * T_CNT * 65;
    const float* fe_base = fe + (size_t)s * T_CNT;
    const float* Ub      = USE_U ? (U + (size_t)s * T_CNT * H_DIM) : nullptr;

    __syncthreads();

    for (int c = 0; c < T_CNT / CH; ++c) {
        const int t0 = c * CH, pc = c & 1;
        if (USE_U) {
            const float4* src = reinterpret_cast<const float4*>(Ub + (size_t)t0 * H_DIM);
            float4* dst = reinterpret_cast<float4*>(&ubuf[0][0]);
#pragma unroll
            for (int k = 0; k < 4; ++k) dst[k * NTHR + tid] = src[k * NTHR + tid];
            if (tid < CH) {
                zbuf[pc][tid]  = in_base[(size_t)(t0 + tid) * 65];
                febuf[pc][tid] = fe_base[t0 + tid];
            }
        } else {
            for (int idx = tid; idx < CH * 65; idx += NTHR) {
                const int row = idx / 65, col = idx - row * 65;
                const float v = in_base[(size_t)(t0 + row) * 65 + col];
                if (col == 0) zbuf[pc][row] = v;
                else          xbuf[row][col - 1] = v;
            }
            if (tid < CH) febuf[pc][tid] = fe_base[t0 + tid];
        }
        __syncthreads();

        for (int tt = 0; tt < CH; ++tt) {
            const int t  = t0 + tt;
            const int rp = (t + 1) & 1;

            // ---- pipelined sigma reduce for step t-1 (even lanes hold values) ----
            {
                float sv = sv_prev;
                sv += __shfl_xor(sv, 2);
                sv += __shfl_xor(sv, 4);
                sv += __shfl_xor(sv, 8);
                sv += __shfl_xor(sv, 16);
                sv += __shfl_xor(sv, 32);
                if (lane == 0) wsum[(t - 1) & 1][wv] = sv;
            }

            // ---- thread0 finalize for step t-2 ----
            if (tid == 0 && t >= 2) {
                const int tm = t - 2;
                const float* wp = wsum[tm & 1];
                float sg = ((wp[0] + wp[1]) + (wp[2] + wp[3])) +
                           ((wp[4] + wp[5]) + (wp[6] + wp[7])) + blin;
                const float sigma = fabsf(sg);
                sig_out[tm] = sigma;
                const int cm = (tm >> 5) & 1, rm = tm & (CH - 1);
                const float diff = zbuf[cm][rm] - febuf[cm][rm];
                ll -= (diff * diff) / (2.f * sigma * sigma);
            }

            // ---- half-row matvec ----
            const float4* hv = reinterpret_cast<const float4*>(&hbuf[rp][half * 128]);
            float a0 = 0.f, a1 = 0.f, a2 = 0.f, a3 = 0.f;
#pragma unroll
            for (int q = 0; q < 32; q += 4) {
                a0 = fma4(whh[q],     hv[q],     a0);
                a1 = fma4(whh[q + 1], hv[q + 1], a1);
                a2 = fma4(whh[q + 2], hv[q + 2], a2);
                a3 = fma4(whh[q + 3], hv[q + 3], a3);
            }
            if (!USE_U) {
                const float4* xv = reinterpret_cast<const float4*>(&xbuf[tt][half * 32]);
#pragma unroll
                for (int q = 0; q < 8; q += 4) {
                    a0 = fma4(wih[q],     xv[q],     a0);
                    a1 = fma4(wih[q + 1], xv[q + 1], a1);
                    a2 = fma4(wih[q + 2], xv[q + 2], a2);
                    a3 = fma4(wih[q + 3], xv[q + 3], a3);
                }
            }
            float dot = (a0 + a1) + (a2 + a3);
            dot += __shfl_xor(dot, 1);
            const float uval = USE_U ? ubuf[tt][j] : bias_lds[j];
            const float h = fast_tanh(dot + uval);
            if (half == 0) hbuf[t & 1][j] = h;
            sv_prev = (half == 0) ? h * wlin_lds[j] : 0.f;
            __syncthreads();
        }
    }

    // ---- epilogue: finalize T-2 and T-1 ----
    {
        float sv = sv_prev;
        sv += __shfl_xor(sv, 2);
        sv += __shfl_xor(sv, 4);
        sv += __shfl_xor(sv, 8);
        sv += __shfl_xor(sv, 16);
        sv += __shfl_xor(sv, 32);
        if (lane == 0) wsum[(T_CNT - 1) & 1][wv] = sv;
    }
    __syncthreads();
    if (tid == 0) {
        for (int tm = T_CNT - 2; tm < T_CNT; ++tm) {
            const float* wp = wsum[tm & 1];
            float sg = ((wp[0] + wp[1]) + (wp[2] + wp[3])) +
                       ((wp[4] + wp[5]) + (wp[6] + wp[7])) + blin;
            const float sigma = fabsf(sg);
            sig_out[tm] = sigma;
            const int cm = (tm >> 5) & 1, rm = tm & (CH - 1);
            const float diff = zbuf[cm][rm] - febuf[cm][rm];
            ll -= (diff * diff) / (2.f * sigma * sigma);
        }
        atomicAdd(out, ll);
    }
}

extern "C" void kernel_launch(void* const* d_in, const int* in_sizes, int n_in,
                              void* d_out, int out_size, void* d_ws, size_t ws_size,
                              hipStream_t stream) {
    (void)in_sizes; (void)n_in; (void)out_size;
    const float* input_data = (const float*)d_in[0];
    const float* hidden     = (const float*)d_in[1];
    const float* fe         = (const float*)d_in[2];
    const float* W_ih       = (const float*)d_in[3];
    const float* W_hh       = (const float*)d_in[4];
    const float* b_ih       = (const float*)d_in[5];
    const float* b_hh       = (const float*)d_in[6];
    const float* W_lin      = (const float*)d_in[7];
    const float* b_lin      = (const float*)d_in[8];
    float* out = (float*)d_out;

    hipMemsetAsync(d_out, 0, sizeof(float), stream);

    const size_t uneed = (size_t)S_CNT * T_CNT * H_DIM * sizeof(float);
    if (ws_size >= uneed) {
        float* U = (float*)d_ws;
        precompute_u_kernel<<<dim3(S_CNT, 4), 256, 0, stream>>>(
            input_data, W_ih, b_ih, b_hh, U);
        rnn_main_kernel<true><<<dim3(S_CNT), dim3(NTHR), 0, stream>>>(
            input_data, hidden, fe, W_ih, W_hh, b_ih, b_hh, W_lin, b_lin, U, out);
    } else {
        rnn_main_kernel<false><<<dim3(S_CNT), dim3(NTHR), 0, stream>>>(
            input_data, hidden, fe, W_ih, W_hh, b_ih, b_hh, W_lin, b_lin,
            (const float*)nullptr, out);
    }
}

// Round 3
// 2148.073 us; speedup vs baseline: 1.4678x; 1.4678x over previous
//
#include <hip/hip_runtime.h>
#include <cmath>

#define S_CNT 50
#define T_CNT 2048
#define I_DIM 64
#define H_DIM 256
#define NTHR  1024

__device__ __forceinline__ float fast_tanh(float x) {
    float e = __expf(2.0f * x);
    return 1.0f - __fdividef(2.0f, e + 1.0f);
}

__device__ __forceinline__ float fma4(const float4 w, const float4 h, float a) {
    a = fmaf(w.x, h.x, a);
    a = fmaf(w.y, h.y, a);
    a = fmaf(w.z, h.z, a);
    a = fmaf(w.w, h.w, a);
    return a;
}

// U[s][t][j] = b_ih[s][j] + b_hh[s][j] + W_ih[s][j]·x[s][t]
__launch_bounds__(256, 4)
__global__ void precompute_u_kernel(const float* __restrict__ input_data,
                                    const float* __restrict__ W_ih,
                                    const float* __restrict__ b_ih,
                                    const float* __restrict__ b_hh,
                                    float* __restrict__ U)
{
    const int s  = blockIdx.x;
    const int tb = blockIdx.y;   // 16 t-slices of 128 steps
    const int j  = threadIdx.x;

    float4 w[16];
    const float4* wrow =
        reinterpret_cast<const float4*>(W_ih + ((size_t)s * H_DIM + j) * I_DIM);
#pragma unroll
    for (int k = 0; k < 16; ++k) w[k] = wrow[k];
    const float bsum = b_ih[s * H_DIM + j] + b_hh[s * H_DIM + j];

    __shared__ float xs[32][I_DIM];
    const float* inb = input_data + (size_t)s * T_CNT * 65;
    float* Ub = U + (size_t)s * T_CNT * H_DIM;

    for (int c = 0; c < 4; ++c) {
        const int t0 = tb * 128 + c * 32;
        __syncthreads();
        for (int idx = j; idx < 32 * I_DIM; idx += 256) {
            const int row = idx >> 6, col = idx & 63;
            xs[row][col] = inb[(size_t)(t0 + row) * 65 + 1 + col];
        }
        __syncthreads();
        for (int tt = 0; tt < 32; ++tt) {
            const float4* xv = reinterpret_cast<const float4*>(&xs[tt][0]);
            float a0 = bsum, a1 = 0.f, a2 = 0.f, a3 = 0.f;
#pragma unroll
            for (int k = 0; k < 16; k += 4) {
                a0 = fma4(w[k],     xv[k],     a0);
                a1 = fma4(w[k + 1], xv[k + 1], a1);
                a2 = fma4(w[k + 2], xv[k + 2], a2);
                a3 = fma4(w[k + 3], xv[k + 3], a3);
            }
            Ub[(size_t)(t0 + tt) * H_DIM + j] = (a0 + a1) + (a2 + a3);
        }
    }
}

// Main recurrence. tid = j*4 + q: thread owns W_hh[j][f*4..f*4+4) for
// float4-indices f = 4m+q, m=0..15 (interleaved striping -> bank-disjoint
// 4-address broadcast reads of h). 64 weight VGPRs/thread: stays in arch
// VGPRs under launch_bounds(1024,4). Sigma reduce pipelined 1 step behind,
// thread0 finalize 2 steps behind. U register-prefetched 1 step ahead.
template <bool USE_U>
__launch_bounds__(NTHR, 4)
__global__ void rnn_main_kernel(const float* __restrict__ input_data,
                                const float* __restrict__ hidden,
                                const float* __restrict__ fe,
                                const float* __restrict__ W_ih,
                                const float* __restrict__ W_hh,
                                const float* __restrict__ b_ih,
                                const float* __restrict__ b_hh,
                                const float* __restrict__ W_lin,
                                const float* __restrict__ b_lin,
                                const float* __restrict__ U,
                                float* __restrict__ out)
{
    const int s    = blockIdx.x;
    const int tid  = threadIdx.x;
    const int j    = tid >> 2;
    const int q    = tid & 3;
    const int lane = tid & 63;
    const int wv   = tid >> 6;   // 0..15

    constexpr int CH = USE_U ? T_CNT : 64;

    __shared__ float hbuf[2][H_DIM];
    __shared__ float zbuf[T_CNT];
    __shared__ float febuf[T_CNT];
    __shared__ float wlin_lds[H_DIM];
    __shared__ float wsum[2][16];
    __shared__ float xbuf[USE_U ? 1 : 64][I_DIM];

    const float* in_base = input_data + (size_t)s * T_CNT * 65;
    const float* fe_base = fe + (size_t)s * T_CNT;

    for (int t = tid; t < T_CNT; t += NTHR) {
        zbuf[t]  = in_base[(size_t)t * 65];
        febuf[t] = fe_base[t];
    }
    if (tid < H_DIM) {
        hbuf[1][tid]  = hidden[s * H_DIM + tid];
        wlin_lds[tid] = W_lin[s * H_DIM + tid];
    }

    // weights: 16 float4, interleaved striping f = 4m+q
    float4 w[16];
    {
        const float4* wrow =
            reinterpret_cast<const float4*>(W_hh + ((size_t)s * H_DIM + j) * H_DIM);
#pragma unroll
        for (int m = 0; m < 16; ++m) w[m] = wrow[4 * m + q];
    }
    float4 wx[4];
    float badd = 0.f;
    if (!USE_U) {
        const float4* wxrow =
            reinterpret_cast<const float4*>(W_ih + ((size_t)s * H_DIM + j) * I_DIM);
#pragma unroll
        for (int m = 0; m < 4; ++m) wx[m] = wxrow[4 * m + q];
        badd = b_ih[s * H_DIM + j] + b_hh[s * H_DIM + j];
    }

    const float blin = b_lin[s];
    const float* Ub  = USE_U ? (U + (size_t)s * T_CNT * H_DIM) : nullptr;
    float* sig_out   = out + 1 + (size_t)s * T_CNT;

    float ll = 0.f, sv_prev = 0.f;
    float ucur = USE_U ? Ub[j] : 0.f;

    __syncthreads();

    for (int c = 0; c < T_CNT / CH; ++c) {
        if (!USE_U) {
            for (int idx = tid; idx < CH * I_DIM; idx += NTHR) {
                const int row = idx >> 6, col = idx & 63;
                xbuf[row][col] = in_base[(size_t)(c * CH + row) * 65 + 1 + col];
            }
            __syncthreads();
        }
        for (int tt = 0; tt < CH; ++tt) {
            const int t  = c * CH + tt;
            const int rp = (t + 1) & 1;

            // prefetch U for t+1 (used next step; latency hidden by matvec)
            float unext = 0.f;
            if (USE_U) {
                const int tn = (t + 1 < T_CNT) ? t + 1 : T_CNT - 1;
                unext = Ub[(size_t)tn * H_DIM + j];
            }

            // pipelined sigma reduce for step t-1 (q-coset sums each j once)
            {
                float sv = sv_prev;
                sv += __shfl_xor(sv, 4);
                sv += __shfl_xor(sv, 8);
                sv += __shfl_xor(sv, 16);
                sv += __shfl_xor(sv, 32);
                if (lane == 0) wsum[(t - 1) & 1][wv] = sv;
            }

            // thread0 finalize for step t-2
            if (tid == 0 && t >= 2) {
                const int tm = t - 2;
                const float* wp = wsum[tm & 1];
                float sg = (((wp[0] + wp[1]) + (wp[2] + wp[3])) +
                            ((wp[4] + wp[5]) + (wp[6] + wp[7]))) +
                           (((wp[8] + wp[9]) + (wp[10] + wp[11])) +
                            ((wp[12] + wp[13]) + (wp[14] + wp[15]))) + blin;
                const float sigma = fabsf(sg);
                sig_out[tm] = sigma;
                const float diff = zbuf[tm] - febuf[tm];
                ll -= (diff * diff) / (2.f * sigma * sigma);
            }

            // matvec: 16 ds_read_b128 + 64 FMA
            const float4* hv = reinterpret_cast<const float4*>(&hbuf[rp][0]);
            float a0 = 0.f, a1 = 0.f, a2 = 0.f, a3 = 0.f;
#pragma unroll
            for (int m = 0; m < 16; m += 4) {
                a0 = fma4(w[m],     hv[4 * (m + 0) + q], a0);
                a1 = fma4(w[m + 1], hv[4 * (m + 1) + q], a1);
                a2 = fma4(w[m + 2], hv[4 * (m + 2) + q], a2);
                a3 = fma4(w[m + 3], hv[4 * (m + 3) + q], a3);
            }
            if (!USE_U) {
                const float4* xv = reinterpret_cast<const float4*>(&xbuf[tt][0]);
#pragma unroll
                for (int m = 0; m < 4; ++m)
                    a0 = fma4(wx[m], xv[4 * m + q], a0);
            }
            float dot = (a0 + a1) + (a2 + a3);
            dot += __shfl_xor(dot, 1);
            dot += __shfl_xor(dot, 2);

            const float h = fast_tanh(dot + (USE_U ? ucur : badd));
            if (q == 0) hbuf[t & 1][j] = h;
            sv_prev = h * wlin_lds[j];
            ucur = unext;
            __syncthreads();
        }
        if (!USE_U) __syncthreads();
    }

    // epilogue: sigma of T-1, then finalize T-2 and T-1
    {
        float sv = sv_prev;
        sv += __shfl_xor(sv, 4);
        sv += __shfl_xor(sv, 8);
        sv += __shfl_xor(sv, 16);
        sv += __shfl_xor(sv, 32);
        if (lane == 0) wsum[(T_CNT - 1) & 1][wv] = sv;
    }
    __syncthreads();
    if (tid == 0) {
        for (int tm = T_CNT - 2; tm < T_CNT; ++tm) {
            const float* wp = wsum[tm & 1];
            float sg = (((wp[0] + wp[1]) + (wp[2] + wp[3])) +
                        ((wp[4] + wp[5]) + (wp[6] + wp[7]))) +
                       (((wp[8] + wp[9]) + (wp[10] + wp[11])) +
                        ((wp[12] + wp[13]) + (wp[14] + wp[15]))) + blin;
            const float sigma = fabsf(sg);
            sig_out[tm] = sigma;
            const float diff = zbuf[tm] - febuf[tm];
            ll -= (diff * diff) / (2.f * sigma * sigma);
        }
        atomicAdd(out, ll);
    }
}

extern "C" void kernel_launch(void* const* d_in, const int* in_sizes, int n_in,
                              void* d_out, int out_size, void* d_ws, size_t ws_size,
                              hipStream_t stream) {
    (void)in_sizes; (void)n_in; (void)out_size;
    const float* input_data = (const float*)d_in[0];
    const float* hidden     = (const float*)d_in[1];
    const float* fe         = (const float*)d_in[2];
    const float* W_ih       = (const float*)d_in[3];
    const float* W_hh       = (const float*)d_in[4];
    const float* b_ih       = (const float*)d_in[5];
    const float* b_hh       = (const float*)d_in[6];
    const float* W_lin      = (const float*)d_in[7];
    const float* b_lin      = (const float*)d_in[8];
    float* out = (float*)d_out;

    hipMemsetAsync(d_out, 0, sizeof(float), stream);

    const size_t uneed = (size_t)S_CNT * T_CNT * H_DIM * sizeof(float);
    if (ws_size >= uneed) {
        float* U = (float*)d_ws;
        precompute_u_kernel<<<dim3(S_CNT, 16), 256, 0, stream>>>(
            input_data, W_ih, b_ih, b_hh, U);
        rnn_main_kernel<true><<<dim3(S_CNT), dim3(NTHR), 0, stream>>>(
            input_data, hidden, fe, W_ih, W_hh, b_ih, b_hh, W_lin, b_lin, U, out);
    } else {
        rnn_main_kernel<false><<<dim3(S_CNT), dim3(NTHR), 0, stream>>>(
            input_data, hidden, fe, W_ih, W_hh, b_ih, b_hh, W_lin, b_lin,
            (const float*)nullptr, out);
    }
}